// Round 1
// baseline (4069.637 us; speedup 1.0000x reference)
//
#include <hip/hip_runtime.h>
#include <math.h>

// ULOSD keypoint autoencoder, fp32 direct convolutions.
// Round 4: latency attack. Round-3 counters: VALUBusy 43%, HBM 4.5%, occupancy
// 36-46% at 128 VGPR (counter reports granules of 4). The ci-loop had a serial
// {9 vmem loads + 72 s_load weights} -> 288 FMA dependency every iteration.
// Changes:
//   (1) per-block LDS weight cache (NC x Cin x 9) -- weight reads become
//       broadcast ds_reads that dual-issue under the FMA stream; kills the
//       per-ci s_load (lgkmcnt) chain.
//   (2) 2-deep ping-pong register prefetch of input rows across ci -- loads for
//       ci+1 issue before the 288 FMAs of ci (~576 cyc of cover).
//   (3) __launch_bounds__(256,4) pin on conv_s1 to hold 4 waves/SIMD.

enum { ACT_ID = 0, ACT_LRELU = 1, ACT_SOFTPLUS = 2, ACT_RELU = 3 };

template<int ACT>
__device__ __forceinline__ float act_fn(float x) {
  if (ACT == ACT_LRELU)    return x >= 0.f ? x : 0.2f * x;
  if (ACT == ACT_SOFTPLUS) return fmaxf(x, 0.f) + log1pf(expf(-fabsf(x)));
  if (ACT == ACT_RELU)     return fmaxf(x, 0.f);
  return x;
}

// ---------------- stride-1 helpers ---------------------------------------------
template<int CPT>
__device__ __forceinline__ void ld_s1(const float* __restrict__ p, int W,
    int y, int ym, int yp, int xl, int x0, int xr,
    bool okT, bool okB, bool okL, bool okR, float (&v)[3][CPT + 2]) {
  #pragma unroll
  for (int dy = 0; dy < 3; ++dy) {
    const int  ry    = (dy == 0) ? ym : ((dy == 1) ? y : yp);
    const bool okRow = (dy == 0) ? okT : ((dy == 1) ? true : okB);
    const float* r = p + ry * W;
    if (CPT == 4) {
      float  lf = r[xl];
      float4 m  = *(const float4*)(r + x0);
      float  rf = r[xr];
      v[dy][0] = (okRow && okL) ? lf : 0.f;
      v[dy][1] = okRow ? m.x : 0.f;
      v[dy][2] = okRow ? m.y : 0.f;
      v[dy][3] = okRow ? m.z : 0.f;
      v[dy][4] = okRow ? m.w : 0.f;
      v[dy][5] = (okRow && okR) ? rf : 0.f;
    } else if (CPT == 2) {
      float  lf = r[xl];
      float2 m  = *(const float2*)(r + x0);   // x0 even -> aligned
      float  rf = r[xr];
      v[dy][0] = (okRow && okL) ? lf : 0.f;
      v[dy][1] = okRow ? m.x : 0.f;
      v[dy][2] = okRow ? m.y : 0.f;
      v[dy][3] = (okRow && okR) ? rf : 0.f;
    } else {
      v[dy][0] = (okRow && okL) ? r[xl] : 0.f;
      #pragma unroll
      for (int q = 0; q < CPT; ++q) v[dy][1 + q] = okRow ? r[x0 + q] : 0.f;
      v[dy][CPT + 1] = (okRow && okR) ? r[xr] : 0.f;
    }
  }
}

template<int NC, int CPT>
__device__ __forceinline__ void fma_s1(const float* wl, int Cin, int ci,
    const float (&v)[3][CPT + 2], float (&acc)[NC][CPT]) {
  #pragma unroll
  for (int u = 0; u < NC; ++u) {
    const float* wp = wl + ((u * Cin + ci) * 9);
    float wr[9];
    #pragma unroll
    for (int k = 0; k < 9; ++k) wr[k] = wp[k];     // broadcast ds_reads
    #pragma unroll
    for (int dy = 0; dy < 3; ++dy)
      #pragma unroll
      for (int q = 0; q < CPT; ++q)
        acc[u][q] += v[dy][q]     * wr[dy * 3]
                   + v[dy][q + 1] * wr[dy * 3 + 1]
                   + v[dy][q + 2] * wr[dy * 3 + 2];
  }
}

// ---------------- stride-1 3x3 SAME conv ---------------------------------------
template<int ACT, int NC, int CPT>
__global__ __launch_bounds__(256, 4)
void conv_s1(const float* __restrict__ in, const float* __restrict__ w,
             const float* __restrict__ bias, float* __restrict__ out,
             int Cin, int Cout, int H, int W) {
  extern __shared__ float wl[];
  const int cogs = Cout / NC;
  const int gx  = blockIdx.x;           // b*cogs + cog
  const int cog = gx % cogs;
  const int b   = gx / cogs;
  const int co0 = cog * NC;

  // stage this block's weights to LDS (all threads; barrier before item guard)
  {
    const float* wg = w + (size_t)co0 * Cin * 9;
    const int total = NC * Cin * 9;
    for (int idx = threadIdx.x; idx < total; idx += 256) wl[idx] = wg[idx];
  }
  __syncthreads();

  const int Wq  = W / CPT;
  const int items = H * Wq;
  const int item  = blockIdx.y * 256 + threadIdx.x;
  if (item >= items) return;
  const int y  = item / Wq;
  const int x0 = (item - y * Wq) * CPT;

  const int HW = H * W;
  const float* ib = in + (size_t)b * Cin * HW;

  const bool okT = (y > 0), okB = (y < H - 1);
  const bool okL = (x0 > 0), okR = (x0 + CPT < W);
  const int ym = okT ? (y - 1) : 0;
  const int yp = okB ? (y + 1) : 0;
  const int xl = okL ? (x0 - 1) : 0;
  const int xr = okR ? (x0 + CPT) : 0;

  float acc[NC][CPT];
  #pragma unroll
  for (int u = 0; u < NC; ++u)
    #pragma unroll
    for (int q = 0; q < CPT; ++q) acc[u][q] = 0.f;

  float va[3][CPT + 2], vb[3][CPT + 2];
  ld_s1<CPT>(ib, W, y, ym, yp, xl, x0, xr, okT, okB, okL, okR, va);

  int ci = 0;
  for (; ci + 2 <= Cin; ci += 2) {
    ld_s1<CPT>(ib + (size_t)(ci + 1) * HW, W, y, ym, yp, xl, x0, xr, okT, okB, okL, okR, vb);
    fma_s1<NC, CPT>(wl, Cin, ci, va, acc);
    if (ci + 2 < Cin)
      ld_s1<CPT>(ib + (size_t)(ci + 2) * HW, W, y, ym, yp, xl, x0, xr, okT, okB, okL, okR, va);
    fma_s1<NC, CPT>(wl, Cin, ci + 1, vb, acc);
  }
  if (ci < Cin) fma_s1<NC, CPT>(wl, Cin, ci, va, acc);   // odd Cin tail (enc0)

  #pragma unroll
  for (int u = 0; u < NC; ++u) {
    const float bv = bias[co0 + u];
    float* op = out + ((size_t)(b * Cout + co0 + u) * H + y) * W + x0;
    if (CPT == 4) {
      float4 r4;
      r4.x = act_fn<ACT>(acc[u][0] + bv);
      r4.y = act_fn<ACT>(acc[u][1] + bv);
      r4.z = act_fn<ACT>(acc[u][2] + bv);
      r4.w = act_fn<ACT>(acc[u][3] + bv);
      *(float4*)op = r4;
    } else if (CPT == 2) {
      float2 r2;
      r2.x = act_fn<ACT>(acc[u][0] + bv);
      r2.y = act_fn<ACT>(acc[u][1] + bv);
      *(float2*)op = r2;
    } else {
      #pragma unroll
      for (int q = 0; q < CPT; ++q) op[q] = act_fn<ACT>(acc[u][q] + bv);
    }
  }
}

// ---------------- stride-2 helpers ---------------------------------------------
template<int CPT>
__device__ __forceinline__ void ld_s2(const float* __restrict__ p, int W,
    int iy0, int iy1, int iy2c, bool okB, int ix, int ixr, bool okR,
    float (&v)[3][2 * CPT + 1]) {
  #pragma unroll
  for (int dy = 0; dy < 3; ++dy) {
    const int  ry    = (dy == 0) ? iy0 : ((dy == 1) ? iy1 : iy2c);
    const bool okRow = (dy < 2) || okB;
    const float* r = p + ry * W;
    if (CPT == 4) {
      float4 m0 = *(const float4*)(r + ix);
      float4 m1 = *(const float4*)(r + ix + 4);
      float  rf = r[ixr];
      v[dy][0] = okRow ? m0.x : 0.f; v[dy][1] = okRow ? m0.y : 0.f;
      v[dy][2] = okRow ? m0.z : 0.f; v[dy][3] = okRow ? m0.w : 0.f;
      v[dy][4] = okRow ? m1.x : 0.f; v[dy][5] = okRow ? m1.y : 0.f;
      v[dy][6] = okRow ? m1.z : 0.f; v[dy][7] = okRow ? m1.w : 0.f;
      v[dy][8] = (okRow && okR) ? rf : 0.f;
    } else if (CPT == 2) {
      float4 m0 = *(const float4*)(r + ix);   // ix % 4 == 0 -> aligned
      float  rf = r[ixr];
      v[dy][0] = okRow ? m0.x : 0.f; v[dy][1] = okRow ? m0.y : 0.f;
      v[dy][2] = okRow ? m0.z : 0.f; v[dy][3] = okRow ? m0.w : 0.f;
      v[dy][4] = (okRow && okR) ? rf : 0.f;
    } else {
      float2 m0 = *(const float2*)(r + ix);   // ix even -> aligned
      float  rf = r[ixr];
      v[dy][0] = okRow ? m0.x : 0.f; v[dy][1] = okRow ? m0.y : 0.f;
      v[dy][2] = (okRow && okR) ? rf : 0.f;
    }
  }
}

template<int NC, int CPT>
__device__ __forceinline__ void fma_s2(const float* wl, int Cin, int ci,
    const float (&v)[3][2 * CPT + 1], float (&acc)[NC][CPT]) {
  #pragma unroll
  for (int u = 0; u < NC; ++u) {
    const float* wp = wl + ((u * Cin + ci) * 9);
    float wr[9];
    #pragma unroll
    for (int k = 0; k < 9; ++k) wr[k] = wp[k];
    #pragma unroll
    for (int dy = 0; dy < 3; ++dy)
      #pragma unroll
      for (int q = 0; q < CPT; ++q)
        acc[u][q] += v[dy][2 * q]     * wr[dy * 3]
                   + v[dy][2 * q + 1] * wr[dy * 3 + 1]
                   + v[dy][2 * q + 2] * wr[dy * 3 + 2];
  }
}

// ---------------- stride-2 3x3 SAME conv (pad_before=0, pad_after=1) -----------
template<int ACT, int NC, int CPT>
__global__ __launch_bounds__(256)
void conv_s2(const float* __restrict__ in, const float* __restrict__ w,
             const float* __restrict__ bias, float* __restrict__ out,
             int Cin, int Cout, int H, int W) {
  extern __shared__ float wl[];
  const int Ho = H >> 1, Wo = W >> 1;
  const int cogs = Cout / NC;
  const int gx  = blockIdx.x;
  const int cog = gx % cogs;
  const int b   = gx / cogs;
  const int co0 = cog * NC;

  {
    const float* wg = w + (size_t)co0 * Cin * 9;
    const int total = NC * Cin * 9;
    for (int idx = threadIdx.x; idx < total; idx += 256) wl[idx] = wg[idx];
  }
  __syncthreads();

  const int Wq  = Wo / CPT;
  const int items = Ho * Wq;
  const int item  = blockIdx.y * 256 + threadIdx.x;
  if (item >= items) return;
  const int y  = item / Wq;
  const int x0 = (item - y * Wq) * CPT;
  const int ix = 2 * x0;

  const int HW = H * W;
  const float* ib = in + (size_t)b * Cin * HW;

  const int iy0 = 2 * y, iy1 = 2 * y + 1, iy2 = 2 * y + 2;
  const bool okB = (iy2 < H);
  const int iy2c = okB ? iy2 : 0;
  const bool okR = (ix + 2 * CPT < W);
  const int ixr  = okR ? (ix + 2 * CPT) : 0;

  float acc[NC][CPT];
  #pragma unroll
  for (int u = 0; u < NC; ++u)
    #pragma unroll
    for (int q = 0; q < CPT; ++q) acc[u][q] = 0.f;

  float va[3][2 * CPT + 1], vb[3][2 * CPT + 1];
  ld_s2<CPT>(ib, W, iy0, iy1, iy2c, okB, ix, ixr, okR, va);

  int ci = 0;
  for (; ci + 2 <= Cin; ci += 2) {
    ld_s2<CPT>(ib + (size_t)(ci + 1) * HW, W, iy0, iy1, iy2c, okB, ix, ixr, okR, vb);
    fma_s2<NC, CPT>(wl, Cin, ci, va, acc);
    if (ci + 2 < Cin)
      ld_s2<CPT>(ib + (size_t)(ci + 2) * HW, W, iy0, iy1, iy2c, okB, ix, ixr, okR, va);
    fma_s2<NC, CPT>(wl, Cin, ci + 1, vb, acc);
  }
  if (ci < Cin) fma_s2<NC, CPT>(wl, Cin, ci, va, acc);

  #pragma unroll
  for (int u = 0; u < NC; ++u) {
    const float bv = bias[co0 + u];
    float* op = out + ((size_t)(b * Cout + co0 + u) * Ho + y) * Wo + x0;
    if (CPT == 4) {
      float4 r4;
      r4.x = act_fn<ACT>(acc[u][0] + bv);
      r4.y = act_fn<ACT>(acc[u][1] + bv);
      r4.z = act_fn<ACT>(acc[u][2] + bv);
      r4.w = act_fn<ACT>(acc[u][3] + bv);
      *(float4*)op = r4;
    } else if (CPT == 2) {
      float2 r2;
      r2.x = act_fn<ACT>(acc[u][0] + bv);
      r2.y = act_fn<ACT>(acc[u][1] + bv);
      *(float2*)op = r2;
    } else {
      #pragma unroll
      for (int q = 0; q < CPT; ++q) op[q] = act_fn<ACT>(acc[u][q] + bv);
    }
  }
}

// ---------------- stride-2 3x3 SAME transposed conv ----------------------------
// out[2i,2j]=xtl*w00+xtr*w02+xbl*w20+xbr*w22; out[2i,2j+1]=xtr*w01+xbr*w21
// out[2i+1,2j]=xbl*w10+xbr*w12;               out[2i+1,2j+1]=xbr*w11
__device__ __forceinline__ void ld_t(const float* __restrict__ p, int Hin,
    int i, int j, int im, int jm, bool okT, bool okL, float (&xv)[4]) {
  float xtl = p[im * Hin + jm];
  float xtr = p[im * Hin + j];
  float xbl = p[i * Hin + jm];
  float xbr = p[i * Hin + j];
  xv[0] = (okT && okL) ? xtl : 0.f;
  xv[1] = okT ? xtr : 0.f;
  xv[2] = okL ? xbl : 0.f;
  xv[3] = xbr;
}

template<int NC>
__device__ __forceinline__ void fma_t(const float* wl, int Cin, int ci,
    const float (&xv)[4],
    float (&a00)[NC], float (&a01)[NC], float (&a10)[NC], float (&a11)[NC]) {
  #pragma unroll
  for (int u = 0; u < NC; ++u) {
    const float* wp = wl + ((u * Cin + ci) * 9);
    float wr[9];
    #pragma unroll
    for (int k = 0; k < 9; ++k) wr[k] = wp[k];
    a00[u] += xv[0] * wr[0] + xv[1] * wr[2] + xv[2] * wr[6] + xv[3] * wr[8];
    a01[u] += xv[1] * wr[1] + xv[3] * wr[7];
    a10[u] += xv[2] * wr[3] + xv[3] * wr[5];
    a11[u] += xv[3] * wr[4];
  }
}

template<int ACT, int NC>
__global__ __launch_bounds__(256)
void tconv(const float* __restrict__ in, const float* __restrict__ w,
           const float* __restrict__ bias, float* __restrict__ out,
           int Cin, int Cout, int Hin) {
  extern __shared__ float wl[];
  const int cogs = Cout / NC;
  const int gx  = blockIdx.x;
  const int cog = gx % cogs;
  const int b   = gx / cogs;
  const int co0 = cog * NC;

  {
    const float* wg = w + (size_t)co0 * Cin * 9;
    const int total = NC * Cin * 9;
    for (int idx = threadIdx.x; idx < total; idx += 256) wl[idx] = wg[idx];
  }
  __syncthreads();

  const int items = Hin * Hin;
  const int item  = blockIdx.y * 256 + threadIdx.x;
  if (item >= items) return;
  const int i = item / Hin;
  const int j = item - i * Hin;

  const float* ib = in + (size_t)b * Cin * items;
  const bool okT = (i > 0), okL = (j > 0);
  const int im = okT ? i - 1 : 0;
  const int jm = okL ? j - 1 : 0;

  float a00[NC], a01[NC], a10[NC], a11[NC];
  #pragma unroll
  for (int u = 0; u < NC; ++u) { a00[u]=0.f; a01[u]=0.f; a10[u]=0.f; a11[u]=0.f; }

  float xa[4], xb[4];
  ld_t(ib, Hin, i, j, im, jm, okT, okL, xa);

  int ci = 0;
  for (; ci + 2 <= Cin; ci += 2) {
    ld_t(ib + (size_t)(ci + 1) * items, Hin, i, j, im, jm, okT, okL, xb);
    fma_t<NC>(wl, Cin, ci, xa, a00, a01, a10, a11);
    if (ci + 2 < Cin)
      ld_t(ib + (size_t)(ci + 2) * items, Hin, i, j, im, jm, okT, okL, xa);
    fma_t<NC>(wl, Cin, ci + 1, xb, a00, a01, a10, a11);
  }
  if (ci < Cin) fma_t<NC>(wl, Cin, ci, xa, a00, a01, a10, a11);

  const int Ho = Hin * 2;
  #pragma unroll
  for (int u = 0; u < NC; ++u) {
    const float bv = bias[co0 + u];
    float* op = out + (size_t)(b * Cout + co0 + u) * Ho * Ho + (2*i) * Ho + 2*j;
    float2 t0, t1;
    t0.x = act_fn<ACT>(a00[u] + bv); t0.y = act_fn<ACT>(a01[u] + bv);
    t1.x = act_fn<ACT>(a10[u] + bv); t1.y = act_fn<ACT>(a11[u] + bv);
    *(float2*)op = t0;
    *(float2*)(op + Ho) = t1;
  }
}

// ---------------- keypoint reductions: S = sum R, Sh = sum R*h, Sw = sum R*w ----
__global__ __launch_bounds__(64)
void kp_reduce(const float* __restrict__ R, float* __restrict__ S,
               float* __restrict__ Sh, float* __restrict__ Sw) {
  const int bk = blockIdx.x;       // b*K + k, 16x16 maps
  const int t = threadIdx.x;       // 64
  const float* p = R + (size_t)bk * 256;
  float s = 0.f, sh = 0.f, sw = 0.f;
  #pragma unroll
  for (int q = 0; q < 4; ++q) {
    int idx = t + q * 64;
    float v = p[idx];
    s  += v;
    sh += v * (float)(idx >> 4);
    sw += v * (float)(idx & 15);
  }
  #pragma unroll
  for (int off = 32; off > 0; off >>= 1) {
    s  += __shfl_down(s, off);
    sh += __shfl_down(sh, off);
    sw += __shfl_down(sw, off);
  }
  if (t == 0) { S[bk] = s; Sh[bk] = sh; Sw[bk] = sw; }
}

// ---------------- gaussian blob maps -------------------------------------------
__global__ __launch_bounds__(256)
void kp_maps(const float* __restrict__ S, const float* __restrict__ Sh,
             const float* __restrict__ Sw, float* __restrict__ maps, int K) {
  const int bk = blockIdx.x;
  const int b = bk / K;
  const int t = threadIdx.x;       // 256 = 16x16
  const float s   = S[bk];
  const float den = S[b * K + (K - 1)];
  const float mu  = s * (1.0f / 256.0f);
  const float c0  = Sh[bk] / den;
  const float c1  = Sw[bk] / den;
  const float u = (float)(t >> 4);
  const float v = (float)(t & 15);
  const float d2 = (u - c0) * (u - c0) + (v - c1) * (v - c1);
  maps[(size_t)bk * 256 + t] = mu * expf(-0.5f * d2);
}

extern "C" void kernel_launch(void* const* d_in, const int* in_sizes, int n_in,
                              void* d_out, int out_size, void* d_ws, size_t ws_size,
                              hipStream_t stream) {
  const int B = 32;  // 4 * 8
  const float* x = (const float*)d_in[0];
  const float* ew[7]; const float* eb[7];
  for (int j = 0; j < 7; ++j) { ew[j] = (const float*)d_in[1 + 2*j]; eb[j] = (const float*)d_in[2 + 2*j]; }
  const float* dw[6]; const float* db[6];
  for (int j = 0; j < 6; ++j) { dw[j] = (const float*)d_in[15 + 2*j]; db[j] = (const float*)d_in[16 + 2*j]; }

  float* ws   = (float*)d_ws;
  float* bufA = ws;                       // 32*32*128*128 = 16,777,216 floats
  float* bufB = bufA + 16777216;
  float* R    = bufB + 16777216;          // 32*128*256 = 1,048,576
  float* maps = R + 1048576;
  float* S    = maps + 1048576;           // 4096
  float* Sh   = S + 4096;
  float* Sw   = Sh + 4096;
  float* outp = (float*)d_out;            // 32*16*128*128

  dim3 blk(256);
  #define WSZ(NC, CIN) ((NC) * (CIN) * 9 * (int)sizeof(float))

  // ---- encoder ----  grid.x = B*(Cout/NC), grid.y = ceil(H*W/CPT/256)
  conv_s1<ACT_ID,      8,4><<<dim3(B*4,  16), blk, WSZ(8,3),   stream>>>(x,    ew[0], eb[0], bufA, 3,   32,  128, 128);
  conv_s1<ACT_ID,      8,4><<<dim3(B*4,  16), blk, WSZ(8,32),  stream>>>(bufA, ew[1], eb[1], bufB, 32,  32,  128, 128);
  conv_s2<ACT_LRELU,   8,4><<<dim3(B*8,   4), blk, WSZ(8,32),  stream>>>(bufB, ew[2], eb[2], bufA, 32,  64,  128, 128);
  conv_s1<ACT_LRELU,   8,4><<<dim3(B*8,   4), blk, WSZ(8,64),  stream>>>(bufA, ew[3], eb[3], bufB, 64,  64,  64,  64);
  conv_s2<ACT_LRELU,   8,2><<<dim3(B*16,  2), blk, WSZ(8,64),  stream>>>(bufB, ew[4], eb[4], bufA, 64,  128, 64,  64);
  conv_s1<ACT_LRELU,   8,2><<<dim3(B*16,  2), blk, WSZ(8,128), stream>>>(bufA, ew[5], eb[5], bufB, 128, 128, 32,  32);
  conv_s2<ACT_SOFTPLUS,4,1><<<dim3(B*32,  1), blk, WSZ(4,128), stream>>>(bufB, ew[6], eb[6], R,    128, 128, 32,  32);

  // ---- keypoint bottleneck ----
  kp_reduce<<<dim3(B*128), dim3(64), 0, stream>>>(R, S, Sh, Sw);
  kp_maps  <<<dim3(B*128), blk, 0, stream>>>(S, Sh, Sw, maps, 128);

  // ---- decoder ----
  tconv<ACT_RELU,   2>  <<<dim3(B*32,  1), blk, WSZ(2,128), stream>>>(maps, dw[0], db[0], bufA, 128, 64, 16);
  conv_s1<ACT_RELU, 4,2><<<dim3(B*16,  2), blk, WSZ(4,64),  stream>>>(bufA, dw[1], db[1], bufB, 64,  64, 32, 32);
  tconv<ACT_RELU,   4>  <<<dim3(B*8,   4), blk, WSZ(4,64),  stream>>>(bufB, dw[2], db[2], bufA, 64,  32, 32);
  conv_s1<ACT_RELU, 8,2><<<dim3(B*4,   8), blk, WSZ(8,32),  stream>>>(bufA, dw[3], db[3], bufB, 32,  32, 64, 64);
  tconv<ACT_RELU,   8>  <<<dim3(B*2,  16), blk, WSZ(8,32),  stream>>>(bufB, dw[4], db[4], bufA, 32,  16, 64);
  conv_s1<ACT_RELU, 8,4><<<dim3(B*2,  16), blk, WSZ(8,16),  stream>>>(bufA, dw[5], db[5], outp, 16,  16, 128, 128);
  #undef WSZ
}

// Round 2
// 1702.609 us; speedup vs baseline: 2.3902x; 2.3902x over previous
//
#include <hip/hip_runtime.h>
#include <math.h>

// ULOSD keypoint autoencoder, fp32 direct convolutions.
// Round 5: round-4 post-mortem showed the register ping-pong + launch_bounds(256,4)
// pin spilled va/vb to scratch (4.7 GB HBM traffic on a 128 MB-footprint layer,
// VALUBusy 12.8%). This round keeps ONLY the LDS weight cache from round 4
// (removes the per-ci s_load latency chains; SGPR 112->48 confirmed it works),
// reverts to the round-3 single-buffer inner loop, and drops the occupancy pin
// so the allocator lands at its natural <=128 VGPRs (4 waves/SIMD).

enum { ACT_ID = 0, ACT_LRELU = 1, ACT_SOFTPLUS = 2, ACT_RELU = 3 };

template<int ACT>
__device__ __forceinline__ float act_fn(float x) {
  if (ACT == ACT_LRELU)    return x >= 0.f ? x : 0.2f * x;
  if (ACT == ACT_SOFTPLUS) return fmaxf(x, 0.f) + log1pf(expf(-fabsf(x)));
  if (ACT == ACT_RELU)     return fmaxf(x, 0.f);
  return x;
}

// ---------------- stride-1 3x3 SAME conv, NC couts x CPT cols per thread -------
template<int ACT, int NC, int CPT>
__global__ __launch_bounds__(256)
void conv_s1(const float* __restrict__ in, const float* __restrict__ w,
             const float* __restrict__ bias, float* __restrict__ out,
             int Cin, int Cout, int H, int W) {
  extern __shared__ float wl[];
  const int cogs = Cout / NC;
  const int gx  = blockIdx.x;           // b*cogs + cog
  const int cog = gx % cogs;
  const int b   = gx / cogs;
  const int co0 = cog * NC;

  // stage this block's NC x Cin x 9 weights to LDS (before item guard!)
  {
    const float* wg = w + (size_t)co0 * Cin * 9;
    const int total = NC * Cin * 9;
    for (int idx = threadIdx.x; idx < total; idx += 256) wl[idx] = wg[idx];
  }
  __syncthreads();

  const int Wq  = W / CPT;
  const int items = H * Wq;
  const int item  = blockIdx.y * 256 + threadIdx.x;
  if (item >= items) return;
  const int y  = item / Wq;
  const int x0 = (item - y * Wq) * CPT;

  const int HW = H * W;
  const float* ib = in + (size_t)b * Cin * HW;

  const bool okT = (y > 0), okB = (y < H - 1);
  const bool okL = (x0 > 0), okR = (x0 + CPT < W);
  const int ym = okT ? (y - 1) : 0;
  const int yp = okB ? (y + 1) : 0;
  const int xl = okL ? (x0 - 1) : 0;
  const int xr = okR ? (x0 + CPT) : 0;

  float acc[NC][CPT];
  #pragma unroll
  for (int u = 0; u < NC; ++u)
    #pragma unroll
    for (int q = 0; q < CPT; ++q) acc[u][q] = 0.f;

  for (int ci = 0; ci < Cin; ++ci) {
    const float* p = ib + ci * HW;
    const float* wci = wl + ci * 9;          // +u*Cin*9 per out-channel
    #pragma unroll
    for (int dy = 0; dy < 3; ++dy) {
      const int  ry    = (dy == 0) ? ym : ((dy == 1) ? y : yp);
      const bool okRow = (dy == 0) ? okT : ((dy == 1) ? true : okB);
      const float* r = p + ry * W;
      float v[CPT + 2];
      if (CPT == 4) {
        float  lf = r[xl];
        float4 m  = *(const float4*)(r + x0);
        float  rf = r[xr];
        v[0] = (okRow && okL) ? lf : 0.f;
        v[1] = okRow ? m.x : 0.f;
        v[2] = okRow ? m.y : 0.f;
        v[3] = okRow ? m.z : 0.f;
        v[4] = okRow ? m.w : 0.f;
        v[5] = (okRow && okR) ? rf : 0.f;
      } else if (CPT == 2) {
        float  lf = r[xl];
        float2 m  = *(const float2*)(r + x0);   // x0 even -> aligned
        float  rf = r[xr];
        v[0] = (okRow && okL) ? lf : 0.f;
        v[1] = okRow ? m.x : 0.f;
        v[2] = okRow ? m.y : 0.f;
        v[3] = (okRow && okR) ? rf : 0.f;
      } else {
        v[0] = (okRow && okL) ? r[xl] : 0.f;
        #pragma unroll
        for (int q = 0; q < CPT; ++q) v[1 + q] = okRow ? r[x0 + q] : 0.f;
        v[CPT + 1] = (okRow && okR) ? r[xr] : 0.f;
      }
      #pragma unroll
      for (int u = 0; u < NC; ++u) {
        const float* wp = wci + u * Cin * 9 + dy * 3;
        const float w0 = wp[0], w1 = wp[1], w2 = wp[2];   // broadcast ds_reads
        #pragma unroll
        for (int q = 0; q < CPT; ++q)
          acc[u][q] += v[q] * w0 + v[q + 1] * w1 + v[q + 2] * w2;
      }
    }
  }

  #pragma unroll
  for (int u = 0; u < NC; ++u) {
    const float bv = bias[co0 + u];
    float* op = out + ((size_t)(b * Cout + co0 + u) * H + y) * W + x0;
    if (CPT == 4) {
      float4 r4;
      r4.x = act_fn<ACT>(acc[u][0] + bv);
      r4.y = act_fn<ACT>(acc[u][1] + bv);
      r4.z = act_fn<ACT>(acc[u][2] + bv);
      r4.w = act_fn<ACT>(acc[u][3] + bv);
      *(float4*)op = r4;
    } else if (CPT == 2) {
      float2 r2;
      r2.x = act_fn<ACT>(acc[u][0] + bv);
      r2.y = act_fn<ACT>(acc[u][1] + bv);
      *(float2*)op = r2;
    } else {
      #pragma unroll
      for (int q = 0; q < CPT; ++q) op[q] = act_fn<ACT>(acc[u][q] + bv);
    }
  }
}

// ---------------- stride-2 3x3 SAME conv (pad_before=0, pad_after=1) -----------
template<int ACT, int NC, int CPT>
__global__ __launch_bounds__(256)
void conv_s2(const float* __restrict__ in, const float* __restrict__ w,
             const float* __restrict__ bias, float* __restrict__ out,
             int Cin, int Cout, int H, int W) {
  extern __shared__ float wl[];
  const int Ho = H >> 1, Wo = W >> 1;
  const int cogs = Cout / NC;
  const int gx  = blockIdx.x;
  const int cog = gx % cogs;
  const int b   = gx / cogs;
  const int co0 = cog * NC;

  {
    const float* wg = w + (size_t)co0 * Cin * 9;
    const int total = NC * Cin * 9;
    for (int idx = threadIdx.x; idx < total; idx += 256) wl[idx] = wg[idx];
  }
  __syncthreads();

  const int Wq  = Wo / CPT;
  const int items = Ho * Wq;
  const int item  = blockIdx.y * 256 + threadIdx.x;
  if (item >= items) return;
  const int y  = item / Wq;
  const int x0 = (item - y * Wq) * CPT;
  const int ix = 2 * x0;                     // input cols ix .. ix+2*CPT

  const int HW = H * W;
  const float* ib = in + (size_t)b * Cin * HW;

  const int iy0 = 2 * y, iy1 = 2 * y + 1, iy2 = 2 * y + 2;
  const bool okB = (iy2 < H);
  const int iy2c = okB ? iy2 : 0;
  const bool okR = (ix + 2 * CPT < W);
  const int ixr  = okR ? (ix + 2 * CPT) : 0;

  float acc[NC][CPT];
  #pragma unroll
  for (int u = 0; u < NC; ++u)
    #pragma unroll
    for (int q = 0; q < CPT; ++q) acc[u][q] = 0.f;

  for (int ci = 0; ci < Cin; ++ci) {
    const float* p = ib + ci * HW;
    const float* wci = wl + ci * 9;
    #pragma unroll
    for (int dy = 0; dy < 3; ++dy) {
      const int  ry    = (dy == 0) ? iy0 : ((dy == 1) ? iy1 : iy2c);
      const bool okRow = (dy < 2) || okB;
      const float* r = p + ry * W;
      float v[2 * CPT + 1];
      if (CPT == 4) {
        float4 m0 = *(const float4*)(r + ix);
        float4 m1 = *(const float4*)(r + ix + 4);
        float  rf = r[ixr];
        v[0] = okRow ? m0.x : 0.f; v[1] = okRow ? m0.y : 0.f;
        v[2] = okRow ? m0.z : 0.f; v[3] = okRow ? m0.w : 0.f;
        v[4] = okRow ? m1.x : 0.f; v[5] = okRow ? m1.y : 0.f;
        v[6] = okRow ? m1.z : 0.f; v[7] = okRow ? m1.w : 0.f;
        v[8] = (okRow && okR) ? rf : 0.f;
      } else if (CPT == 2) {
        float4 m0 = *(const float4*)(r + ix);   // ix % 4 == 0 -> aligned
        float  rf = r[ixr];
        v[0] = okRow ? m0.x : 0.f; v[1] = okRow ? m0.y : 0.f;
        v[2] = okRow ? m0.z : 0.f; v[3] = okRow ? m0.w : 0.f;
        v[4] = (okRow && okR) ? rf : 0.f;
      } else if (CPT == 1) {
        float2 m0 = *(const float2*)(r + ix);   // ix even -> aligned
        float  rf = r[ixr];
        v[0] = okRow ? m0.x : 0.f; v[1] = okRow ? m0.y : 0.f;
        v[2] = (okRow && okR) ? rf : 0.f;
      } else {
        #pragma unroll
        for (int q = 0; q < 2 * CPT; ++q) v[q] = okRow ? r[ix + q] : 0.f;
        v[2 * CPT] = (okRow && okR) ? r[ixr] : 0.f;
      }
      #pragma unroll
      for (int u = 0; u < NC; ++u) {
        const float* wp = wci + u * Cin * 9 + dy * 3;
        const float w0 = wp[0], w1 = wp[1], w2 = wp[2];
        #pragma unroll
        for (int q = 0; q < CPT; ++q)
          acc[u][q] += v[2*q] * w0 + v[2*q + 1] * w1 + v[2*q + 2] * w2;
      }
    }
  }

  #pragma unroll
  for (int u = 0; u < NC; ++u) {
    const float bv = bias[co0 + u];
    float* op = out + ((size_t)(b * Cout + co0 + u) * Ho + y) * Wo + x0;
    if (CPT == 4) {
      float4 r4;
      r4.x = act_fn<ACT>(acc[u][0] + bv);
      r4.y = act_fn<ACT>(acc[u][1] + bv);
      r4.z = act_fn<ACT>(acc[u][2] + bv);
      r4.w = act_fn<ACT>(acc[u][3] + bv);
      *(float4*)op = r4;
    } else if (CPT == 2) {
      float2 r2;
      r2.x = act_fn<ACT>(acc[u][0] + bv);
      r2.y = act_fn<ACT>(acc[u][1] + bv);
      *(float2*)op = r2;
    } else {
      #pragma unroll
      for (int q = 0; q < CPT; ++q) op[q] = act_fn<ACT>(acc[u][q] + bv);
    }
  }
}

// ---------------- stride-2 3x3 SAME transposed conv ----------------------------
// out[2i,2j]=xtl*w00+xtr*w02+xbl*w20+xbr*w22; out[2i,2j+1]=xtr*w01+xbr*w21
// out[2i+1,2j]=xbl*w10+xbr*w12;               out[2i+1,2j+1]=xbr*w11
template<int ACT, int NC>
__global__ __launch_bounds__(256)
void tconv(const float* __restrict__ in, const float* __restrict__ w,
           const float* __restrict__ bias, float* __restrict__ out,
           int Cin, int Cout, int Hin) {
  extern __shared__ float wl[];
  const int cogs = Cout / NC;
  const int gx  = blockIdx.x;
  const int cog = gx % cogs;
  const int b   = gx / cogs;
  const int co0 = cog * NC;

  {
    const float* wg = w + (size_t)co0 * Cin * 9;
    const int total = NC * Cin * 9;
    for (int idx = threadIdx.x; idx < total; idx += 256) wl[idx] = wg[idx];
  }
  __syncthreads();

  const int items = Hin * Hin;
  const int item  = blockIdx.y * 256 + threadIdx.x;
  if (item >= items) return;
  const int i = item / Hin;
  const int j = item - i * Hin;

  const float* ib = in + (size_t)b * Cin * items;
  const bool okT = (i > 0), okL = (j > 0);
  const int im = okT ? i - 1 : 0;
  const int jm = okL ? j - 1 : 0;

  float a00[NC], a01[NC], a10[NC], a11[NC];
  #pragma unroll
  for (int u = 0; u < NC; ++u) { a00[u]=0.f; a01[u]=0.f; a10[u]=0.f; a11[u]=0.f; }

  for (int ci = 0; ci < Cin; ++ci) {
    const float* p = ib + ci * items;
    float xtl = p[im*Hin + jm]; xtl = (okT && okL) ? xtl : 0.f;
    float xtr = p[im*Hin + j];  xtr = okT ? xtr : 0.f;
    float xbl = p[i*Hin + jm];  xbl = okL ? xbl : 0.f;
    float xbr = p[i*Hin + j];
    const float* wci = wl + ci * 9;
    #pragma unroll
    for (int u = 0; u < NC; ++u) {
      const float* wp = wci + u * Cin * 9;
      const float w00 = wp[0], w01 = wp[1], w02 = wp[2];
      const float w10 = wp[3], w11 = wp[4], w12 = wp[5];
      const float w20 = wp[6], w21 = wp[7], w22 = wp[8];
      a00[u] += xtl*w00 + xtr*w02 + xbl*w20 + xbr*w22;
      a01[u] += xtr*w01 + xbr*w21;
      a10[u] += xbl*w10 + xbr*w12;
      a11[u] += xbr*w11;
    }
  }

  const int Ho = Hin * 2;
  #pragma unroll
  for (int u = 0; u < NC; ++u) {
    const float bv = bias[co0 + u];
    float* op = out + (size_t)(b * Cout + co0 + u) * Ho * Ho + (2*i) * Ho + 2*j;
    float2 t0, t1;
    t0.x = act_fn<ACT>(a00[u] + bv); t0.y = act_fn<ACT>(a01[u] + bv);
    t1.x = act_fn<ACT>(a10[u] + bv); t1.y = act_fn<ACT>(a11[u] + bv);
    *(float2*)op = t0;
    *(float2*)(op + Ho) = t1;
  }
}

// ---------------- keypoint reductions: S = sum R, Sh = sum R*h, Sw = sum R*w ----
__global__ __launch_bounds__(64)
void kp_reduce(const float* __restrict__ R, float* __restrict__ S,
               float* __restrict__ Sh, float* __restrict__ Sw) {
  const int bk = blockIdx.x;       // b*K + k, 16x16 maps
  const int t = threadIdx.x;       // 64
  const float* p = R + (size_t)bk * 256;
  float s = 0.f, sh = 0.f, sw = 0.f;
  #pragma unroll
  for (int q = 0; q < 4; ++q) {
    int idx = t + q * 64;
    float v = p[idx];
    s  += v;
    sh += v * (float)(idx >> 4);
    sw += v * (float)(idx & 15);
  }
  #pragma unroll
  for (int off = 32; off > 0; off >>= 1) {
    s  += __shfl_down(s, off);
    sh += __shfl_down(sh, off);
    sw += __shfl_down(sw, off);
  }
  if (t == 0) { S[bk] = s; Sh[bk] = sh; Sw[bk] = sw; }
}

// ---------------- gaussian blob maps -------------------------------------------
__global__ __launch_bounds__(256)
void kp_maps(const float* __restrict__ S, const float* __restrict__ Sh,
             const float* __restrict__ Sw, float* __restrict__ maps, int K) {
  const int bk = blockIdx.x;
  const int b = bk / K;
  const int t = threadIdx.x;       // 256 = 16x16
  const float s   = S[bk];
  const float den = S[b * K + (K - 1)];
  const float mu  = s * (1.0f / 256.0f);
  const float c0  = Sh[bk] / den;
  const float c1  = Sw[bk] / den;
  const float u = (float)(t >> 4);
  const float v = (float)(t & 15);
  const float d2 = (u - c0) * (u - c0) + (v - c1) * (v - c1);
  maps[(size_t)bk * 256 + t] = mu * expf(-0.5f * d2);
}

extern "C" void kernel_launch(void* const* d_in, const int* in_sizes, int n_in,
                              void* d_out, int out_size, void* d_ws, size_t ws_size,
                              hipStream_t stream) {
  const int B = 32;  // 4 * 8
  const float* x = (const float*)d_in[0];
  const float* ew[7]; const float* eb[7];
  for (int j = 0; j < 7; ++j) { ew[j] = (const float*)d_in[1 + 2*j]; eb[j] = (const float*)d_in[2 + 2*j]; }
  const float* dw[6]; const float* db[6];
  for (int j = 0; j < 6; ++j) { dw[j] = (const float*)d_in[15 + 2*j]; db[j] = (const float*)d_in[16 + 2*j]; }

  float* ws   = (float*)d_ws;
  float* bufA = ws;                       // 32*32*128*128 = 16,777,216 floats
  float* bufB = bufA + 16777216;
  float* R    = bufB + 16777216;          // 32*128*256 = 1,048,576
  float* maps = R + 1048576;
  float* S    = maps + 1048576;           // 4096
  float* Sh   = S + 4096;
  float* Sw   = Sh + 4096;
  float* outp = (float*)d_out;            // 32*16*128*128

  dim3 blk(256);
  #define WSZ(NC, CIN) ((NC) * (CIN) * 9 * (int)sizeof(float))

  // ---- encoder ----  grid.x = B*(Cout/NC), grid.y = ceil(H*W/CPT/256)
  conv_s1<ACT_ID,      8,4><<<dim3(B*4,  16), blk, WSZ(8,3),   stream>>>(x,    ew[0], eb[0], bufA, 3,   32,  128, 128);
  conv_s1<ACT_ID,      8,4><<<dim3(B*4,  16), blk, WSZ(8,32),  stream>>>(bufA, ew[1], eb[1], bufB, 32,  32,  128, 128);
  conv_s2<ACT_LRELU,   8,4><<<dim3(B*8,   4), blk, WSZ(8,32),  stream>>>(bufB, ew[2], eb[2], bufA, 32,  64,  128, 128);
  conv_s1<ACT_LRELU,   8,4><<<dim3(B*8,   4), blk, WSZ(8,64),  stream>>>(bufA, ew[3], eb[3], bufB, 64,  64,  64,  64);
  conv_s2<ACT_LRELU,   8,2><<<dim3(B*16,  2), blk, WSZ(8,64),  stream>>>(bufB, ew[4], eb[4], bufA, 64,  128, 64,  64);
  conv_s1<ACT_LRELU,   8,2><<<dim3(B*16,  2), blk, WSZ(8,128), stream>>>(bufA, ew[5], eb[5], bufB, 128, 128, 32,  32);
  conv_s2<ACT_SOFTPLUS,4,1><<<dim3(B*32,  1), blk, WSZ(4,128), stream>>>(bufB, ew[6], eb[6], R,    128, 128, 32,  32);

  // ---- keypoint bottleneck ----
  kp_reduce<<<dim3(B*128), dim3(64), 0, stream>>>(R, S, Sh, Sw);
  kp_maps  <<<dim3(B*128), blk, 0, stream>>>(S, Sh, Sw, maps, 128);

  // ---- decoder ----
  tconv<ACT_RELU,   2>  <<<dim3(B*32,  1), blk, WSZ(2,128), stream>>>(maps, dw[0], db[0], bufA, 128, 64, 16);
  conv_s1<ACT_RELU, 4,2><<<dim3(B*16,  2), blk, WSZ(4,64),  stream>>>(bufA, dw[1], db[1], bufB, 64,  64, 32, 32);
  tconv<ACT_RELU,   4>  <<<dim3(B*8,   4), blk, WSZ(4,64),  stream>>>(bufB, dw[2], db[2], bufA, 64,  32, 32);
  conv_s1<ACT_RELU, 8,2><<<dim3(B*4,   8), blk, WSZ(8,32),  stream>>>(bufA, dw[3], db[3], bufB, 32,  32, 64, 64);
  tconv<ACT_RELU,   8>  <<<dim3(B*2,  16), blk, WSZ(8,32),  stream>>>(bufB, dw[4], db[4], bufA, 32,  16, 64);
  conv_s1<ACT_RELU, 8,4><<<dim3(B*2,  16), blk, WSZ(8,16),  stream>>>(bufA, dw[5], db[5], outp, 16,  16, 128, 128);
  #undef WSZ
}

// Round 3
// 1300.642 us; speedup vs baseline: 3.1289x; 1.3091x over previous
//
#include <hip/hip_runtime.h>
#include <math.h>

// ULOSD keypoint autoencoder, fp32 direct convolutions.
// Round 6: revert LDS weight cache (round 5: VGPR 32->88, occupancy 36->20%,
// 283->297 us -- ds_read weights cost VGPRs and occupancy; scalar s_load path
// is better). Real round-3 defect: runtime Cin = no unroll = serial
// {loads -> waitcnt -> 288 FMA} per ci with a full memory latency exposed each
// iteration. Fix: compile-time CIN template + #pragma unroll 2 on the ci loop
// (4 for tconv) so the compiler pipelines iteration i+1's loads under
// iteration i's FMAs. No persistent register arrays (round-4 lesson), no
// occupancy pin.

enum { ACT_ID = 0, ACT_LRELU = 1, ACT_SOFTPLUS = 2, ACT_RELU = 3 };

template<int ACT>
__device__ __forceinline__ float act_fn(float x) {
  if (ACT == ACT_LRELU)    return x >= 0.f ? x : 0.2f * x;
  if (ACT == ACT_SOFTPLUS) return fmaxf(x, 0.f) + log1pf(expf(-fabsf(x)));
  if (ACT == ACT_RELU)     return fmaxf(x, 0.f);
  return x;
}

// ---------------- stride-1 3x3 SAME conv, NC couts x CPT cols per thread -------
template<int ACT, int NC, int CPT, int CIN>
__global__ __launch_bounds__(256)
void conv_s1(const float* __restrict__ in, const float* __restrict__ w,
             const float* __restrict__ bias, float* __restrict__ out,
             int Cout, int H, int W) {
  const int cogs = Cout / NC;
  const int gx  = blockIdx.x;           // b*cogs + cog
  const int cog = gx % cogs;
  const int b   = gx / cogs;
  const int co0 = cog * NC;
  const int Wq  = W / CPT;
  const int items = H * Wq;
  const int item  = blockIdx.y * 256 + threadIdx.x;
  if (item >= items) return;
  const int y  = item / Wq;
  const int x0 = (item - y * Wq) * CPT;

  const int HW = H * W;
  const float* ib = in + (size_t)b * CIN * HW;

  const bool okT = (y > 0), okB = (y < H - 1);
  const bool okL = (x0 > 0), okR = (x0 + CPT < W);
  const int ym = okT ? (y - 1) : 0;
  const int yp = okB ? (y + 1) : 0;
  const int xl = okL ? (x0 - 1) : 0;
  const int xr = okR ? (x0 + CPT) : 0;

  float acc[NC][CPT];
  #pragma unroll
  for (int u = 0; u < NC; ++u)
    #pragma unroll
    for (int q = 0; q < CPT; ++q) acc[u][q] = 0.f;

  #pragma unroll 2
  for (int ci = 0; ci < CIN; ++ci) {
    const float* p = ib + ci * HW;
    const float* wci = w + ((size_t)co0 * CIN + ci) * 9;  // +u*CIN*9 per cout
    #pragma unroll
    for (int dy = 0; dy < 3; ++dy) {
      const int  ry    = (dy == 0) ? ym : ((dy == 1) ? y : yp);
      const bool okRow = (dy == 0) ? okT : ((dy == 1) ? true : okB);
      const float* r = p + ry * W;
      float v[CPT + 2];
      if (CPT == 4) {
        float  lf = r[xl];
        float4 m  = *(const float4*)(r + x0);
        float  rf = r[xr];
        v[0] = (okRow && okL) ? lf : 0.f;
        v[1] = okRow ? m.x : 0.f;
        v[2] = okRow ? m.y : 0.f;
        v[3] = okRow ? m.z : 0.f;
        v[4] = okRow ? m.w : 0.f;
        v[5] = (okRow && okR) ? rf : 0.f;
      } else if (CPT == 2) {
        float  lf = r[xl];
        float2 m  = *(const float2*)(r + x0);   // x0 even -> aligned
        float  rf = r[xr];
        v[0] = (okRow && okL) ? lf : 0.f;
        v[1] = okRow ? m.x : 0.f;
        v[2] = okRow ? m.y : 0.f;
        v[3] = (okRow && okR) ? rf : 0.f;
      } else {
        v[0] = (okRow && okL) ? r[xl] : 0.f;
        #pragma unroll
        for (int q = 0; q < CPT; ++q) v[1 + q] = okRow ? r[x0 + q] : 0.f;
        v[CPT + 1] = (okRow && okR) ? r[xr] : 0.f;
      }
      #pragma unroll
      for (int u = 0; u < NC; ++u) {
        const float* wp = wci + u * CIN * 9 + dy * 3;
        const float w0 = wp[0], w1 = wp[1], w2 = wp[2];   // wave-uniform s_loads
        #pragma unroll
        for (int q = 0; q < CPT; ++q)
          acc[u][q] += v[q] * w0 + v[q + 1] * w1 + v[q + 2] * w2;
      }
    }
  }

  #pragma unroll
  for (int u = 0; u < NC; ++u) {
    const float bv = bias[co0 + u];
    float* op = out + ((size_t)(b * Cout + co0 + u) * H + y) * W + x0;
    if (CPT == 4) {
      float4 r4;
      r4.x = act_fn<ACT>(acc[u][0] + bv);
      r4.y = act_fn<ACT>(acc[u][1] + bv);
      r4.z = act_fn<ACT>(acc[u][2] + bv);
      r4.w = act_fn<ACT>(acc[u][3] + bv);
      *(float4*)op = r4;
    } else if (CPT == 2) {
      float2 r2;
      r2.x = act_fn<ACT>(acc[u][0] + bv);
      r2.y = act_fn<ACT>(acc[u][1] + bv);
      *(float2*)op = r2;
    } else {
      #pragma unroll
      for (int q = 0; q < CPT; ++q) op[q] = act_fn<ACT>(acc[u][q] + bv);
    }
  }
}

// ---------------- stride-2 3x3 SAME conv (pad_before=0, pad_after=1) -----------
template<int ACT, int NC, int CPT, int CIN>
__global__ __launch_bounds__(256)
void conv_s2(const float* __restrict__ in, const float* __restrict__ w,
             const float* __restrict__ bias, float* __restrict__ out,
             int Cout, int H, int W) {
  const int Ho = H >> 1, Wo = W >> 1;
  const int cogs = Cout / NC;
  const int gx  = blockIdx.x;
  const int cog = gx % cogs;
  const int b   = gx / cogs;
  const int co0 = cog * NC;
  const int Wq  = Wo / CPT;
  const int items = Ho * Wq;
  const int item  = blockIdx.y * 256 + threadIdx.x;
  if (item >= items) return;
  const int y  = item / Wq;
  const int x0 = (item - y * Wq) * CPT;
  const int ix = 2 * x0;                     // input cols ix .. ix+2*CPT

  const int HW = H * W;
  const float* ib = in + (size_t)b * CIN * HW;

  const int iy0 = 2 * y, iy1 = 2 * y + 1, iy2 = 2 * y + 2;
  const bool okB = (iy2 < H);
  const int iy2c = okB ? iy2 : 0;
  const bool okR = (ix + 2 * CPT < W);
  const int ixr  = okR ? (ix + 2 * CPT) : 0;

  float acc[NC][CPT];
  #pragma unroll
  for (int u = 0; u < NC; ++u)
    #pragma unroll
    for (int q = 0; q < CPT; ++q) acc[u][q] = 0.f;

  #pragma unroll 2
  for (int ci = 0; ci < CIN; ++ci) {
    const float* p = ib + ci * HW;
    const float* wci = w + ((size_t)co0 * CIN + ci) * 9;
    #pragma unroll
    for (int dy = 0; dy < 3; ++dy) {
      const int  ry    = (dy == 0) ? iy0 : ((dy == 1) ? iy1 : iy2c);
      const bool okRow = (dy < 2) || okB;
      const float* r = p + ry * W;
      float v[2 * CPT + 1];
      if (CPT == 4) {
        float4 m0 = *(const float4*)(r + ix);
        float4 m1 = *(const float4*)(r + ix + 4);
        float  rf = r[ixr];
        v[0] = okRow ? m0.x : 0.f; v[1] = okRow ? m0.y : 0.f;
        v[2] = okRow ? m0.z : 0.f; v[3] = okRow ? m0.w : 0.f;
        v[4] = okRow ? m1.x : 0.f; v[5] = okRow ? m1.y : 0.f;
        v[6] = okRow ? m1.z : 0.f; v[7] = okRow ? m1.w : 0.f;
        v[8] = (okRow && okR) ? rf : 0.f;
      } else if (CPT == 2) {
        float4 m0 = *(const float4*)(r + ix);   // ix % 4 == 0 -> aligned
        float  rf = r[ixr];
        v[0] = okRow ? m0.x : 0.f; v[1] = okRow ? m0.y : 0.f;
        v[2] = okRow ? m0.z : 0.f; v[3] = okRow ? m0.w : 0.f;
        v[4] = (okRow && okR) ? rf : 0.f;
      } else if (CPT == 1) {
        float2 m0 = *(const float2*)(r + ix);   // ix even -> aligned
        float  rf = r[ixr];
        v[0] = okRow ? m0.x : 0.f; v[1] = okRow ? m0.y : 0.f;
        v[2] = (okRow && okR) ? rf : 0.f;
      } else {
        #pragma unroll
        for (int q = 0; q < 2 * CPT; ++q) v[q] = okRow ? r[ix + q] : 0.f;
        v[2 * CPT] = (okRow && okR) ? r[ixr] : 0.f;
      }
      #pragma unroll
      for (int u = 0; u < NC; ++u) {
        const float* wp = wci + u * CIN * 9 + dy * 3;
        const float w0 = wp[0], w1 = wp[1], w2 = wp[2];
        #pragma unroll
        for (int q = 0; q < CPT; ++q)
          acc[u][q] += v[2*q] * w0 + v[2*q + 1] * w1 + v[2*q + 2] * w2;
      }
    }
  }

  #pragma unroll
  for (int u = 0; u < NC; ++u) {
    const float bv = bias[co0 + u];
    float* op = out + ((size_t)(b * Cout + co0 + u) * Ho + y) * Wo + x0;
    if (CPT == 4) {
      float4 r4;
      r4.x = act_fn<ACT>(acc[u][0] + bv);
      r4.y = act_fn<ACT>(acc[u][1] + bv);
      r4.z = act_fn<ACT>(acc[u][2] + bv);
      r4.w = act_fn<ACT>(acc[u][3] + bv);
      *(float4*)op = r4;
    } else if (CPT == 2) {
      float2 r2;
      r2.x = act_fn<ACT>(acc[u][0] + bv);
      r2.y = act_fn<ACT>(acc[u][1] + bv);
      *(float2*)op = r2;
    } else {
      #pragma unroll
      for (int q = 0; q < CPT; ++q) op[q] = act_fn<ACT>(acc[u][q] + bv);
    }
  }
}

// ---------------- stride-2 3x3 SAME transposed conv ----------------------------
// out[2i,2j]=xtl*w00+xtr*w02+xbl*w20+xbr*w22; out[2i,2j+1]=xtr*w01+xbr*w21
// out[2i+1,2j]=xbl*w10+xbr*w12;               out[2i+1,2j+1]=xbr*w11
template<int ACT, int NC, int CIN>
__global__ __launch_bounds__(256)
void tconv(const float* __restrict__ in, const float* __restrict__ w,
           const float* __restrict__ bias, float* __restrict__ out,
           int Cout, int Hin) {
  const int cogs = Cout / NC;
  const int gx  = blockIdx.x;
  const int cog = gx % cogs;
  const int b   = gx / cogs;
  const int co0 = cog * NC;
  const int items = Hin * Hin;
  const int item  = blockIdx.y * 256 + threadIdx.x;
  if (item >= items) return;
  const int i = item / Hin;
  const int j = item - i * Hin;

  const float* ib = in + (size_t)b * CIN * items;
  const bool okT = (i > 0), okL = (j > 0);
  const int im = okT ? i - 1 : 0;
  const int jm = okL ? j - 1 : 0;

  float a00[NC], a01[NC], a10[NC], a11[NC];
  #pragma unroll
  for (int u = 0; u < NC; ++u) { a00[u]=0.f; a01[u]=0.f; a10[u]=0.f; a11[u]=0.f; }

  #pragma unroll 4
  for (int ci = 0; ci < CIN; ++ci) {
    const float* p = ib + ci * items;
    float xtl = p[im*Hin + jm]; xtl = (okT && okL) ? xtl : 0.f;
    float xtr = p[im*Hin + j];  xtr = okT ? xtr : 0.f;
    float xbl = p[i*Hin + jm];  xbl = okL ? xbl : 0.f;
    float xbr = p[i*Hin + j];
    const float* wci = w + ((size_t)co0 * CIN + ci) * 9;
    #pragma unroll
    for (int u = 0; u < NC; ++u) {
      const float* wp = wci + u * CIN * 9;
      const float w00 = wp[0], w01 = wp[1], w02 = wp[2];
      const float w10 = wp[3], w11 = wp[4], w12 = wp[5];
      const float w20 = wp[6], w21 = wp[7], w22 = wp[8];
      a00[u] += xtl*w00 + xtr*w02 + xbl*w20 + xbr*w22;
      a01[u] += xtr*w01 + xbr*w21;
      a10[u] += xbl*w10 + xbr*w12;
      a11[u] += xbr*w11;
    }
  }

  const int Ho = Hin * 2;
  #pragma unroll
  for (int u = 0; u < NC; ++u) {
    const float bv = bias[co0 + u];
    float* op = out + (size_t)(b * Cout + co0 + u) * Ho * Ho + (2*i) * Ho + 2*j;
    float2 t0, t1;
    t0.x = act_fn<ACT>(a00[u] + bv); t0.y = act_fn<ACT>(a01[u] + bv);
    t1.x = act_fn<ACT>(a10[u] + bv); t1.y = act_fn<ACT>(a11[u] + bv);
    *(float2*)op = t0;
    *(float2*)(op + Ho) = t1;
  }
}

// ---------------- keypoint reductions: S = sum R, Sh = sum R*h, Sw = sum R*w ----
__global__ __launch_bounds__(64)
void kp_reduce(const float* __restrict__ R, float* __restrict__ S,
               float* __restrict__ Sh, float* __restrict__ Sw) {
  const int bk = blockIdx.x;       // b*K + k, 16x16 maps
  const int t = threadIdx.x;       // 64
  const float* p = R + (size_t)bk * 256;
  float s = 0.f, sh = 0.f, sw = 0.f;
  #pragma unroll
  for (int q = 0; q < 4; ++q) {
    int idx = t + q * 64;
    float v = p[idx];
    s  += v;
    sh += v * (float)(idx >> 4);
    sw += v * (float)(idx & 15);
  }
  #pragma unroll
  for (int off = 32; off > 0; off >>= 1) {
    s  += __shfl_down(s, off);
    sh += __shfl_down(sh, off);
    sw += __shfl_down(sw, off);
  }
  if (t == 0) { S[bk] = s; Sh[bk] = sh; Sw[bk] = sw; }
}

// ---------------- gaussian blob maps -------------------------------------------
__global__ __launch_bounds__(256)
void kp_maps(const float* __restrict__ S, const float* __restrict__ Sh,
             const float* __restrict__ Sw, float* __restrict__ maps, int K) {
  const int bk = blockIdx.x;
  const int b = bk / K;
  const int t = threadIdx.x;       // 256 = 16x16
  const float s   = S[bk];
  const float den = S[b * K + (K - 1)];
  const float mu  = s * (1.0f / 256.0f);
  const float c0  = Sh[bk] / den;
  const float c1  = Sw[bk] / den;
  const float u = (float)(t >> 4);
  const float v = (float)(t & 15);
  const float d2 = (u - c0) * (u - c0) + (v - c1) * (v - c1);
  maps[(size_t)bk * 256 + t] = mu * expf(-0.5f * d2);
}

extern "C" void kernel_launch(void* const* d_in, const int* in_sizes, int n_in,
                              void* d_out, int out_size, void* d_ws, size_t ws_size,
                              hipStream_t stream) {
  const int B = 32;  // 4 * 8
  const float* x = (const float*)d_in[0];
  const float* ew[7]; const float* eb[7];
  for (int j = 0; j < 7; ++j) { ew[j] = (const float*)d_in[1 + 2*j]; eb[j] = (const float*)d_in[2 + 2*j]; }
  const float* dw[6]; const float* db[6];
  for (int j = 0; j < 6; ++j) { dw[j] = (const float*)d_in[15 + 2*j]; db[j] = (const float*)d_in[16 + 2*j]; }

  float* ws   = (float*)d_ws;
  float* bufA = ws;                       // 32*32*128*128 = 16,777,216 floats
  float* bufB = bufA + 16777216;
  float* R    = bufB + 16777216;          // 32*128*256 = 1,048,576
  float* maps = R + 1048576;
  float* S    = maps + 1048576;           // 4096
  float* Sh   = S + 4096;
  float* Sw   = Sh + 4096;
  float* outp = (float*)d_out;            // 32*16*128*128

  dim3 blk(256);

  // ---- encoder ----  grid.x = B*(Cout/NC), grid.y = ceil(H*W/CPT/256)
  conv_s1<ACT_ID,      8,4,3>  <<<dim3(B*4,  16), blk, 0, stream>>>(x,    ew[0], eb[0], bufA, 32,  128, 128);
  conv_s1<ACT_ID,      8,4,32> <<<dim3(B*4,  16), blk, 0, stream>>>(bufA, ew[1], eb[1], bufB, 32,  128, 128);
  conv_s2<ACT_LRELU,   8,4,32> <<<dim3(B*8,   4), blk, 0, stream>>>(bufB, ew[2], eb[2], bufA, 64,  128, 128);
  conv_s1<ACT_LRELU,   8,4,64> <<<dim3(B*8,   4), blk, 0, stream>>>(bufA, ew[3], eb[3], bufB, 64,  64,  64);
  conv_s2<ACT_LRELU,   8,2,64> <<<dim3(B*16,  2), blk, 0, stream>>>(bufB, ew[4], eb[4], bufA, 128, 64,  64);
  conv_s1<ACT_LRELU,   8,2,128><<<dim3(B*16,  2), blk, 0, stream>>>(bufA, ew[5], eb[5], bufB, 128, 32,  32);
  conv_s2<ACT_SOFTPLUS,4,1,128><<<dim3(B*32,  1), blk, 0, stream>>>(bufB, ew[6], eb[6], R,    128, 32,  32);

  // ---- keypoint bottleneck ----
  kp_reduce<<<dim3(B*128), dim3(64), 0, stream>>>(R, S, Sh, Sw);
  kp_maps  <<<dim3(B*128), blk, 0, stream>>>(S, Sh, Sw, maps, 128);

  // ---- decoder ----
  tconv<ACT_RELU,   2,128><<<dim3(B*32,  1), blk, 0, stream>>>(maps, dw[0], db[0], bufA, 64, 16);
  conv_s1<ACT_RELU, 4,2,64><<<dim3(B*16,  2), blk, 0, stream>>>(bufA, dw[1], db[1], bufB, 64, 32, 32);
  tconv<ACT_RELU,   4,64> <<<dim3(B*8,   4), blk, 0, stream>>>(bufB, dw[2], db[2], bufA, 32, 32);
  conv_s1<ACT_RELU, 8,2,32><<<dim3(B*4,   8), blk, 0, stream>>>(bufA, dw[3], db[3], bufB, 32, 64, 64);
  tconv<ACT_RELU,   8,32> <<<dim3(B*2,  16), blk, 0, stream>>>(bufB, dw[4], db[4], bufA, 16, 64);
  conv_s1<ACT_RELU, 8,4,16><<<dim3(B*2,  16), blk, 0, stream>>>(bufA, dw[5], db[5], outp, 16, 128, 128);
}

// Round 4
// 1206.917 us; speedup vs baseline: 3.3719x; 1.0777x over previous
//
#include <hip/hip_runtime.h>
#include <math.h>

// ULOSD keypoint autoencoder, fp32 direct convolutions.
// Round 7: vertical 2-row output tiling (conv_s1r2) with per-input-row
// processing. Round-6 counters: flagship VALUBusy 70%, VGPR 176 (granule 44),
// 2 waves/SIMD, FETCH 140 MB -- unroll-2's 36 live loaded floats cap the wave
// count. r2 structure: input row r feeds out-row0 (wrow r) and out-row1
// (wrow r-1); only 6 loaded floats live at once, loads/output 4.5->3, FMA
// block per ci doubles (576 cyc), ci loop NOT unrolled (register protection).
// acc 64 + v 6 + addr ~= 110 regs -> 4 waves/SIMD.
// tconv unroll 4->2 (de-risk round-6's unexplained +70us on small layers).

enum { ACT_ID = 0, ACT_LRELU = 1, ACT_SOFTPLUS = 2, ACT_RELU = 3 };

template<int ACT>
__device__ __forceinline__ float act_fn(float x) {
  if (ACT == ACT_LRELU)    return x >= 0.f ? x : 0.2f * x;
  if (ACT == ACT_SOFTPLUS) return fmaxf(x, 0.f) + log1pf(expf(-fabsf(x)));
  if (ACT == ACT_RELU)     return fmaxf(x, 0.f);
  return x;
}

// ---------------- stride-1 3x3 SAME conv, 2 output rows x CPT cols, NC couts ---
template<int ACT, int NC, int CPT, int CIN>
__global__ __launch_bounds__(256)
void conv_s1r2(const float* __restrict__ in, const float* __restrict__ w,
               const float* __restrict__ bias, float* __restrict__ out,
               int Cout, int H, int W) {
  const int cogs = Cout / NC;
  const int gx  = blockIdx.x;           // b*cogs + cog
  const int cog = gx % cogs;
  const int b   = gx / cogs;
  const int co0 = cog * NC;
  const int Wq  = W / CPT;
  const int Hp  = H >> 1;               // row pairs
  const int items = Hp * Wq;
  const int item  = blockIdx.y * 256 + threadIdx.x;
  if (item >= items) return;
  const int yp = item / Wq;
  const int x0 = (item - yp * Wq) * CPT;
  const int y0 = 2 * yp;                // output rows y0, y0+1; input y0-1..y0+2

  const int HW = H * W;
  const float* ib = in + (size_t)b * CIN * HW;

  const bool okT = (y0 > 0), okB = (y0 + 2 < H);
  const bool okL = (x0 > 0), okR = (x0 + CPT < W);
  const int xl = okL ? (x0 - 1) : 0;
  const int xr = okR ? (x0 + CPT) : 0;

  float acc[NC][2][CPT];
  #pragma unroll
  for (int u = 0; u < NC; ++u)
    #pragma unroll
    for (int o = 0; o < 2; ++o)
      #pragma unroll
      for (int q = 0; q < CPT; ++q) acc[u][o][q] = 0.f;

  #pragma unroll 1
  for (int ci = 0; ci < CIN; ++ci) {
    const float* p = ib + ci * HW;
    const float* wci = w + ((size_t)co0 * CIN + ci) * 9;
    #pragma unroll
    for (int r = 0; r < 4; ++r) {            // input rows y0-1+r
      const bool ok = (r == 0) ? okT : ((r == 3) ? okB : true);
      const int iy = ok ? (y0 - 1 + r) : 0;
      const float* row = p + iy * W;
      float v[CPT + 2];
      if (CPT == 4) {
        float  lf = row[xl];
        float4 m  = *(const float4*)(row + x0);
        float  rf = row[xr];
        v[0] = (ok && okL) ? lf : 0.f;
        v[1] = ok ? m.x : 0.f;
        v[2] = ok ? m.y : 0.f;
        v[3] = ok ? m.z : 0.f;
        v[4] = ok ? m.w : 0.f;
        v[5] = (ok && okR) ? rf : 0.f;
      } else if (CPT == 2) {
        float  lf = row[xl];
        float2 m  = *(const float2*)(row + x0);   // x0 even -> aligned
        float  rf = row[xr];
        v[0] = (ok && okL) ? lf : 0.f;
        v[1] = ok ? m.x : 0.f;
        v[2] = ok ? m.y : 0.f;
        v[3] = (ok && okR) ? rf : 0.f;
      } else {
        v[0] = (ok && okL) ? row[xl] : 0.f;
        #pragma unroll
        for (int q = 0; q < CPT; ++q) v[1 + q] = ok ? row[x0 + q] : 0.f;
        v[CPT + 1] = (ok && okR) ? row[xr] : 0.f;
      }
      // input row r -> out-row0 with wrow r (r<=2), out-row1 with wrow r-1 (r>=1)
      #pragma unroll
      for (int u = 0; u < NC; ++u) {
        const float* wp = wci + (size_t)u * CIN * 9;   // wave-uniform s_loads
        if (r <= 2) {
          const float w0 = wp[r * 3], w1 = wp[r * 3 + 1], w2 = wp[r * 3 + 2];
          #pragma unroll
          for (int q = 0; q < CPT; ++q)
            acc[u][0][q] += v[q] * w0 + v[q + 1] * w1 + v[q + 2] * w2;
        }
        if (r >= 1) {
          const float w0 = wp[(r-1) * 3], w1 = wp[(r-1) * 3 + 1], w2 = wp[(r-1) * 3 + 2];
          #pragma unroll
          for (int q = 0; q < CPT; ++q)
            acc[u][1][q] += v[q] * w0 + v[q + 1] * w1 + v[q + 2] * w2;
        }
      }
    }
  }

  #pragma unroll
  for (int u = 0; u < NC; ++u) {
    const float bv = bias[co0 + u];
    float* op = out + ((size_t)(b * Cout + co0 + u) * H + y0) * W + x0;
    #pragma unroll
    for (int o = 0; o < 2; ++o) {
      float* opo = op + o * W;
      if (CPT == 4) {
        float4 r4;
        r4.x = act_fn<ACT>(acc[u][o][0] + bv);
        r4.y = act_fn<ACT>(acc[u][o][1] + bv);
        r4.z = act_fn<ACT>(acc[u][o][2] + bv);
        r4.w = act_fn<ACT>(acc[u][o][3] + bv);
        *(float4*)opo = r4;
      } else if (CPT == 2) {
        float2 r2;
        r2.x = act_fn<ACT>(acc[u][o][0] + bv);
        r2.y = act_fn<ACT>(acc[u][o][1] + bv);
        *(float2*)opo = r2;
      } else {
        #pragma unroll
        for (int q = 0; q < CPT; ++q) opo[q] = act_fn<ACT>(acc[u][o][q] + bv);
      }
    }
  }
}

// ---------------- stride-1 3x3 SAME conv, 1 row (round-6 path, dec1 only) ------
template<int ACT, int NC, int CPT, int CIN>
__global__ __launch_bounds__(256)
void conv_s1(const float* __restrict__ in, const float* __restrict__ w,
             const float* __restrict__ bias, float* __restrict__ out,
             int Cout, int H, int W) {
  const int cogs = Cout / NC;
  const int gx  = blockIdx.x;
  const int cog = gx % cogs;
  const int b   = gx / cogs;
  const int co0 = cog * NC;
  const int Wq  = W / CPT;
  const int items = H * Wq;
  const int item  = blockIdx.y * 256 + threadIdx.x;
  if (item >= items) return;
  const int y  = item / Wq;
  const int x0 = (item - y * Wq) * CPT;

  const int HW = H * W;
  const float* ib = in + (size_t)b * CIN * HW;

  const bool okT = (y > 0), okB = (y < H - 1);
  const bool okL = (x0 > 0), okR = (x0 + CPT < W);
  const int ym = okT ? (y - 1) : 0;
  const int yp = okB ? (y + 1) : 0;
  const int xl = okL ? (x0 - 1) : 0;
  const int xr = okR ? (x0 + CPT) : 0;

  float acc[NC][CPT];
  #pragma unroll
  for (int u = 0; u < NC; ++u)
    #pragma unroll
    for (int q = 0; q < CPT; ++q) acc[u][q] = 0.f;

  #pragma unroll 2
  for (int ci = 0; ci < CIN; ++ci) {
    const float* p = ib + ci * HW;
    const float* wci = w + ((size_t)co0 * CIN + ci) * 9;
    #pragma unroll
    for (int dy = 0; dy < 3; ++dy) {
      const int  ry    = (dy == 0) ? ym : ((dy == 1) ? y : yp);
      const bool okRow = (dy == 0) ? okT : ((dy == 1) ? true : okB);
      const float* r = p + ry * W;
      float v[CPT + 2];
      if (CPT == 2) {
        float  lf = r[xl];
        float2 m  = *(const float2*)(r + x0);
        float  rf = r[xr];
        v[0] = (okRow && okL) ? lf : 0.f;
        v[1] = okRow ? m.x : 0.f;
        v[2] = okRow ? m.y : 0.f;
        v[3] = (okRow && okR) ? rf : 0.f;
      } else {
        v[0] = (okRow && okL) ? r[xl] : 0.f;
        #pragma unroll
        for (int q = 0; q < CPT; ++q) v[1 + q] = okRow ? r[x0 + q] : 0.f;
        v[CPT + 1] = (okRow && okR) ? r[xr] : 0.f;
      }
      #pragma unroll
      for (int u = 0; u < NC; ++u) {
        const float* wp = wci + u * CIN * 9 + dy * 3;
        const float w0 = wp[0], w1 = wp[1], w2 = wp[2];
        #pragma unroll
        for (int q = 0; q < CPT; ++q)
          acc[u][q] += v[q] * w0 + v[q + 1] * w1 + v[q + 2] * w2;
      }
    }
  }

  #pragma unroll
  for (int u = 0; u < NC; ++u) {
    const float bv = bias[co0 + u];
    float* op = out + ((size_t)(b * Cout + co0 + u) * H + y) * W + x0;
    if (CPT == 2) {
      float2 r2;
      r2.x = act_fn<ACT>(acc[u][0] + bv);
      r2.y = act_fn<ACT>(acc[u][1] + bv);
      *(float2*)op = r2;
    } else {
      #pragma unroll
      for (int q = 0; q < CPT; ++q) op[q] = act_fn<ACT>(acc[u][q] + bv);
    }
  }
}

// ---------------- stride-2 3x3 SAME conv (pad_before=0, pad_after=1) -----------
template<int ACT, int NC, int CPT, int CIN>
__global__ __launch_bounds__(256)
void conv_s2(const float* __restrict__ in, const float* __restrict__ w,
             const float* __restrict__ bias, float* __restrict__ out,
             int Cout, int H, int W) {
  const int Ho = H >> 1, Wo = W >> 1;
  const int cogs = Cout / NC;
  const int gx  = blockIdx.x;
  const int cog = gx % cogs;
  const int b   = gx / cogs;
  const int co0 = cog * NC;
  const int Wq  = Wo / CPT;
  const int items = Ho * Wq;
  const int item  = blockIdx.y * 256 + threadIdx.x;
  if (item >= items) return;
  const int y  = item / Wq;
  const int x0 = (item - y * Wq) * CPT;
  const int ix = 2 * x0;

  const int HW = H * W;
  const float* ib = in + (size_t)b * CIN * HW;

  const int iy0 = 2 * y, iy1 = 2 * y + 1, iy2 = 2 * y + 2;
  const bool okB = (iy2 < H);
  const int iy2c = okB ? iy2 : 0;
  const bool okR = (ix + 2 * CPT < W);
  const int ixr  = okR ? (ix + 2 * CPT) : 0;

  float acc[NC][CPT];
  #pragma unroll
  for (int u = 0; u < NC; ++u)
    #pragma unroll
    for (int q = 0; q < CPT; ++q) acc[u][q] = 0.f;

  #pragma unroll 2
  for (int ci = 0; ci < CIN; ++ci) {
    const float* p = ib + ci * HW;
    const float* wci = w + ((size_t)co0 * CIN + ci) * 9;
    #pragma unroll
    for (int dy = 0; dy < 3; ++dy) {
      const int  ry    = (dy == 0) ? iy0 : ((dy == 1) ? iy1 : iy2c);
      const bool okRow = (dy < 2) || okB;
      const float* r = p + ry * W;
      float v[2 * CPT + 1];
      if (CPT == 4) {
        float4 m0 = *(const float4*)(r + ix);
        float4 m1 = *(const float4*)(r + ix + 4);
        float  rf = r[ixr];
        v[0] = okRow ? m0.x : 0.f; v[1] = okRow ? m0.y : 0.f;
        v[2] = okRow ? m0.z : 0.f; v[3] = okRow ? m0.w : 0.f;
        v[4] = okRow ? m1.x : 0.f; v[5] = okRow ? m1.y : 0.f;
        v[6] = okRow ? m1.z : 0.f; v[7] = okRow ? m1.w : 0.f;
        v[8] = (okRow && okR) ? rf : 0.f;
      } else if (CPT == 2) {
        float4 m0 = *(const float4*)(r + ix);
        float  rf = r[ixr];
        v[0] = okRow ? m0.x : 0.f; v[1] = okRow ? m0.y : 0.f;
        v[2] = okRow ? m0.z : 0.f; v[3] = okRow ? m0.w : 0.f;
        v[4] = (okRow && okR) ? rf : 0.f;
      } else {
        float2 m0 = *(const float2*)(r + ix);
        float  rf = r[ixr];
        v[0] = okRow ? m0.x : 0.f; v[1] = okRow ? m0.y : 0.f;
        v[2] = (okRow && okR) ? rf : 0.f;
      }
      #pragma unroll
      for (int u = 0; u < NC; ++u) {
        const float* wp = wci + u * CIN * 9 + dy * 3;
        const float w0 = wp[0], w1 = wp[1], w2 = wp[2];
        #pragma unroll
        for (int q = 0; q < CPT; ++q)
          acc[u][q] += v[2*q] * w0 + v[2*q + 1] * w1 + v[2*q + 2] * w2;
      }
    }
  }

  #pragma unroll
  for (int u = 0; u < NC; ++u) {
    const float bv = bias[co0 + u];
    float* op = out + ((size_t)(b * Cout + co0 + u) * Ho + y) * Wo + x0;
    if (CPT == 4) {
      float4 r4;
      r4.x = act_fn<ACT>(acc[u][0] + bv);
      r4.y = act_fn<ACT>(acc[u][1] + bv);
      r4.z = act_fn<ACT>(acc[u][2] + bv);
      r4.w = act_fn<ACT>(acc[u][3] + bv);
      *(float4*)op = r4;
    } else if (CPT == 2) {
      float2 r2;
      r2.x = act_fn<ACT>(acc[u][0] + bv);
      r2.y = act_fn<ACT>(acc[u][1] + bv);
      *(float2*)op = r2;
    } else {
      #pragma unroll
      for (int q = 0; q < CPT; ++q) op[q] = act_fn<ACT>(acc[u][q] + bv);
    }
  }
}

// ---------------- stride-2 3x3 SAME transposed conv ----------------------------
// out[2i,2j]=xtl*w00+xtr*w02+xbl*w20+xbr*w22; out[2i,2j+1]=xtr*w01+xbr*w21
// out[2i+1,2j]=xbl*w10+xbr*w12;               out[2i+1,2j+1]=xbr*w11
template<int ACT, int NC, int CIN>
__global__ __launch_bounds__(256)
void tconv(const float* __restrict__ in, const float* __restrict__ w,
           const float* __restrict__ bias, float* __restrict__ out,
           int Cout, int Hin) {
  const int cogs = Cout / NC;
  const int gx  = blockIdx.x;
  const int cog = gx % cogs;
  const int b   = gx / cogs;
  const int co0 = cog * NC;
  const int items = Hin * Hin;
  const int item  = blockIdx.y * 256 + threadIdx.x;
  if (item >= items) return;
  const int i = item / Hin;
  const int j = item - i * Hin;

  const float* ib = in + (size_t)b * CIN * items;
  const bool okT = (i > 0), okL = (j > 0);
  const int im = okT ? i - 1 : 0;
  const int jm = okL ? j - 1 : 0;

  float a00[NC], a01[NC], a10[NC], a11[NC];
  #pragma unroll
  for (int u = 0; u < NC; ++u) { a00[u]=0.f; a01[u]=0.f; a10[u]=0.f; a11[u]=0.f; }

  #pragma unroll 2
  for (int ci = 0; ci < CIN; ++ci) {
    const float* p = ib + ci * items;
    float xtl = p[im*Hin + jm]; xtl = (okT && okL) ? xtl : 0.f;
    float xtr = p[im*Hin + j];  xtr = okT ? xtr : 0.f;
    float xbl = p[i*Hin + jm];  xbl = okL ? xbl : 0.f;
    float xbr = p[i*Hin + j];
    const float* wci = w + ((size_t)co0 * CIN + ci) * 9;
    #pragma unroll
    for (int u = 0; u < NC; ++u) {
      const float* wp = wci + u * CIN * 9;
      const float w00 = wp[0], w01 = wp[1], w02 = wp[2];
      const float w10 = wp[3], w11 = wp[4], w12 = wp[5];
      const float w20 = wp[6], w21 = wp[7], w22 = wp[8];
      a00[u] += xtl*w00 + xtr*w02 + xbl*w20 + xbr*w22;
      a01[u] += xtr*w01 + xbr*w21;
      a10[u] += xbl*w10 + xbr*w12;
      a11[u] += xbr*w11;
    }
  }

  const int Ho = Hin * 2;
  #pragma unroll
  for (int u = 0; u < NC; ++u) {
    const float bv = bias[co0 + u];
    float* op = out + (size_t)(b * Cout + co0 + u) * Ho * Ho + (2*i) * Ho + 2*j;
    float2 t0, t1;
    t0.x = act_fn<ACT>(a00[u] + bv); t0.y = act_fn<ACT>(a01[u] + bv);
    t1.x = act_fn<ACT>(a10[u] + bv); t1.y = act_fn<ACT>(a11[u] + bv);
    *(float2*)op = t0;
    *(float2*)(op + Ho) = t1;
  }
}

// ---------------- keypoint reductions: S = sum R, Sh = sum R*h, Sw = sum R*w ----
__global__ __launch_bounds__(64)
void kp_reduce(const float* __restrict__ R, float* __restrict__ S,
               float* __restrict__ Sh, float* __restrict__ Sw) {
  const int bk = blockIdx.x;       // b*K + k, 16x16 maps
  const int t = threadIdx.x;       // 64
  const float* p = R + (size_t)bk * 256;
  float s = 0.f, sh = 0.f, sw = 0.f;
  #pragma unroll
  for (int q = 0; q < 4; ++q) {
    int idx = t + q * 64;
    float v = p[idx];
    s  += v;
    sh += v * (float)(idx >> 4);
    sw += v * (float)(idx & 15);
  }
  #pragma unroll
  for (int off = 32; off > 0; off >>= 1) {
    s  += __shfl_down(s, off);
    sh += __shfl_down(sh, off);
    sw += __shfl_down(sw, off);
  }
  if (t == 0) { S[bk] = s; Sh[bk] = sh; Sw[bk] = sw; }
}

// ---------------- gaussian blob maps -------------------------------------------
__global__ __launch_bounds__(256)
void kp_maps(const float* __restrict__ S, const float* __restrict__ Sh,
             const float* __restrict__ Sw, float* __restrict__ maps, int K) {
  const int bk = blockIdx.x;
  const int b = bk / K;
  const int t = threadIdx.x;       // 256 = 16x16
  const float s   = S[bk];
  const float den = S[b * K + (K - 1)];
  const float mu  = s * (1.0f / 256.0f);
  const float c0  = Sh[bk] / den;
  const float c1  = Sw[bk] / den;
  const float u = (float)(t >> 4);
  const float v = (float)(t & 15);
  const float d2 = (u - c0) * (u - c0) + (v - c1) * (v - c1);
  maps[(size_t)bk * 256 + t] = mu * expf(-0.5f * d2);
}

extern "C" void kernel_launch(void* const* d_in, const int* in_sizes, int n_in,
                              void* d_out, int out_size, void* d_ws, size_t ws_size,
                              hipStream_t stream) {
  const int B = 32;  // 4 * 8
  const float* x = (const float*)d_in[0];
  const float* ew[7]; const float* eb[7];
  for (int j = 0; j < 7; ++j) { ew[j] = (const float*)d_in[1 + 2*j]; eb[j] = (const float*)d_in[2 + 2*j]; }
  const float* dw[6]; const float* db[6];
  for (int j = 0; j < 6; ++j) { dw[j] = (const float*)d_in[15 + 2*j]; db[j] = (const float*)d_in[16 + 2*j]; }

  float* ws   = (float*)d_ws;
  float* bufA = ws;                       // 32*32*128*128 = 16,777,216 floats
  float* bufB = bufA + 16777216;
  float* R    = bufB + 16777216;          // 32*128*256 = 1,048,576
  float* maps = R + 1048576;
  float* S    = maps + 1048576;           // 4096
  float* Sh   = S + 4096;
  float* Sw   = Sh + 4096;
  float* outp = (float*)d_out;            // 32*16*128*128

  dim3 blk(256);

  // ---- encoder ----  r2: grid.x = B*(Cout/NC), grid.y = ceil((H/2)*(W/CPT)/256)
  conv_s1r2<ACT_ID,    8,4,3>  <<<dim3(B*4,   8), blk, 0, stream>>>(x,    ew[0], eb[0], bufA, 32,  128, 128); // 1024 blk
  conv_s1r2<ACT_ID,    8,4,32> <<<dim3(B*4,   8), blk, 0, stream>>>(bufA, ew[1], eb[1], bufB, 32,  128, 128); // 1024 blk
  conv_s2<ACT_LRELU,   8,4,32> <<<dim3(B*8,   4), blk, 0, stream>>>(bufB, ew[2], eb[2], bufA, 64,  128, 128); // 1024 blk
  conv_s1r2<ACT_LRELU, 4,4,64> <<<dim3(B*16,  2), blk, 0, stream>>>(bufA, ew[3], eb[3], bufB, 64,  64,  64);  // 1024 blk
  conv_s2<ACT_LRELU,   8,2,64> <<<dim3(B*16,  2), blk, 0, stream>>>(bufB, ew[4], eb[4], bufA, 128, 64,  64);  // 1024 blk
  conv_s1r2<ACT_LRELU, 4,2,128><<<dim3(B*32,  1), blk, 0, stream>>>(bufA, ew[5], eb[5], bufB, 128, 32,  32);  // 1024 blk
  conv_s2<ACT_SOFTPLUS,4,1,128><<<dim3(B*32,  1), blk, 0, stream>>>(bufB, ew[6], eb[6], R,    128, 32,  32);  // 1024 blk

  // ---- keypoint bottleneck ----
  kp_reduce<<<dim3(B*128), dim3(64), 0, stream>>>(R, S, Sh, Sw);
  kp_maps  <<<dim3(B*128), blk, 0, stream>>>(S, Sh, Sw, maps, 128);

  // ---- decoder ----
  tconv<ACT_RELU,   2,128> <<<dim3(B*32,  1), blk, 0, stream>>>(maps, dw[0], db[0], bufA, 64, 16);            // 1024 blk
  conv_s1<ACT_RELU, 4,2,64><<<dim3(B*16,  2), blk, 0, stream>>>(bufA, dw[1], db[1], bufB, 64, 32, 32);        // 1024 blk
  tconv<ACT_RELU,   4,64>  <<<dim3(B*8,   4), blk, 0, stream>>>(bufB, dw[2], db[2], bufA, 32, 32);            // 1024 blk
  conv_s1r2<ACT_RELU,4,2,32><<<dim3(B*8,   4), blk, 0, stream>>>(bufA, dw[3], db[3], bufB, 32, 64, 64);       // 1024 blk
  tconv<ACT_RELU,   8,32>  <<<dim3(B*2,  16), blk, 0, stream>>>(bufB, dw[4], db[4], bufA, 16, 64);            // 1024 blk
  conv_s1r2<ACT_RELU,4,4,16><<<dim3(B*4,   8), blk, 0, stream>>>(bufA, dw[5], db[5], outp, 16, 128, 128);     // 1024 blk
}